// Round 14
// baseline (285.624 us; speedup 1.0000x reference)
//
#include <hip/hip_runtime.h>
#include <hip/hip_bf16.h>
#include <cstdint>
#include <cstddef>

#define KDIM 4096   // IN_F
#define NDIM 4096   // OUT_F

typedef __attribute__((ext_vector_type(8))) short short8;
typedef __attribute__((ext_vector_type(8))) __bf16 bf16x8;
typedef __attribute__((ext_vector_type(4))) float f32x4;

// f32 -> bf16, round-to-nearest-even
__device__ __forceinline__ unsigned short bf16_rne(float f) {
    unsigned int u = __builtin_bit_cast(unsigned int, f);
    u += 0x7fffu + ((u >> 16) & 1u);
    return (unsigned short)(u >> 16);
}

__device__ __forceinline__ void gload_lds16(const unsigned short* g, unsigned short* l) {
    __builtin_amdgcn_global_load_lds(
        (const __attribute__((address_space(1))) unsigned int*)g,
        (__attribute__((address_space(3))) unsigned int*)l,
        16, 0, 0);
}

// ---------------- preprocess: x fp32 -> bf16 ----------------
__global__ void cvt_x_kernel(const float* __restrict__ x, unsigned short* __restrict__ xb) {
    long i = (long)blockIdx.x * blockDim.x + threadIdx.x;   // one thread = 8 elems
    float4 a = ((const float4*)x)[2 * i];
    float4 b = ((const float4*)x)[2 * i + 1];
    union { unsigned short u[8]; short8 v; } r;
    r.u[0] = bf16_rne(a.x); r.u[1] = bf16_rne(a.y);
    r.u[2] = bf16_rne(a.z); r.u[3] = bf16_rne(a.w);
    r.u[4] = bf16_rne(b.x); r.u[5] = bf16_rne(b.y);
    r.u[6] = bf16_rne(b.z); r.u[7] = bf16_rne(b.w);
    ((short8*)xb)[i] = r.v;
}

// ---------------- preprocess: dequant 2-bit W -> bf16 [N][K] ----------------
__global__ void dequant_w_kernel(const int* __restrict__ wp,
                                 const float* __restrict__ scales,
                                 const float* __restrict__ zeros,
                                 unsigned short* __restrict__ wb) {
    long i = (long)blockIdx.x * blockDim.x + threadIdx.x;   // one thread = 2 packed ints = 8 weights
    int2 p = ((const int2*)wp)[i];
    long base = i * 8;                    // flat weight index (o*4096 + k)
    int o = (int)(base >> 12);
    int g = (int)((base & 4095) >> 7);    // all 8 weights in same group (8 | 128)
    float s = scales[o * 32 + g];
    float z = zeros[o * 32 + g];
    union { unsigned short u[8]; short8 v; } r;
#pragma unroll
    for (int j = 0; j < 4; ++j) {
        r.u[j]     = bf16_rne((float)((p.x >> (2 * j)) & 3) * s + z);
        r.u[4 + j] = bf16_rne((float)((p.y >> (2 * j)) & 3) * s + z);
    }
    ((short8*)wb)[i] = r.v;
}

// ---------------- 256x256 8-phase GEMM, READ-BEHIND (R14) ----------------
// C[M][N] = A[M][K](bf16) * B[N][K](bf16)^T + bias.
// R14 = R12/R13 stage ring + vmcnt constants UNCHANGED; the ds_reads are
// moved to AFTER each phase's MFMA cluster (same sched region, no pin) and
// feed the NEXT phase's MFMAs. The reads then drain UNDER the MFMA epoch +
// barrier wait, so the next phase's compiler lgkm gate is already satisfied.
// This removes the ~2100cy/tile read-drain epoch that every R7-R13 variant
// paid (all had reads feeding the SAME phase's MFMAs => global read epoch).
//
// READ MAP (reads at phase END, consumed next phase):
//  prologue: aF(0), bQ0(0).
//  P1-end: bQ1(e)[4]   P2-end: aG(e)[8]    P3-end: --
//  P4-end (after vmcnt6+bar => buf1 resident): aF(o)[8], bQ0(o)[4]
//  P5-end: bQ1(o)[4]   P6-end: aG(o)[8]    P7-end: --
//  P8-end (after vmcnt4+bar => buf0(e+2) resident): aF(e2)[8], bQ0(e2)[4]
// REGISTER WAR (rewrite after last use): bQ1 P1w/P2u/P5w; aG P2w/P3,P4u/P6w;
//  aF P4w/P5,P6u/P8w; bQ0 P4w/P5,P7u/P8w. All per-wave program order. OK.
// LDS W-A-R: each read returns before its consumer MFMA (compiler lgkm gate)
//  < that phase's end barrier < the overwriting stage (ring: Bn23 staged P4,
//  read P1-end; Ah1 staged P5, read P2-end; buf1 regions staged next-iter
//  P1/P7 >= consumer phases P5-P7). Verified per region.
// STAGE RING + VMCNT (R11/R12, unchanged): P1: A0(o),A1(o)->buf1 | P3:
//  B0(e2) | P4: B1(e2),A0(e2), VMCNT(6) => tile o resident | P5: A1(e2) |
//  P7: B0(o2) | P8: B1(o2), VMCNT(4) => buf0(e+2) resident.
//  Prologue: tile0(8)->buf0, B(1)(4)->buf1, vmcnt(4). Tail: clamp =>
//  byte-idempotent restage (P8 tail reads dead); post-loop vmcnt+lgkm(0).
// Swizzle (proven, 0 conflicts): LDS(r,8j)=G(r,8*(j^(r&7))); read elem
//  R*64 + 8*((4s+lk4)^(R&7)), R&7 == lane&7.

#define PH_BAR \
    __builtin_amdgcn_s_barrier();

#define PH_END \
    __builtin_amdgcn_s_setprio(0); \
    __builtin_amdgcn_sched_barrier(0); \
    __builtin_amdgcn_s_barrier();

#define VMCNT(N) \
    __builtin_amdgcn_sched_barrier(0); \
    asm volatile("s_waitcnt vmcnt(" #N ")" ::: "memory"); \
    __builtin_amdgcn_sched_barrier(0);

#define RD_A(arr, DOFF, mh) \
    _Pragma("unroll") \
    for (int mi_ = 0; mi_ < 4; ++mi_) { \
        arr[mi_][0] = *(const short8*)&sm[(DOFF) + aBase + ((mh)*4 + mi_) * 1024 + sw0]; \
        arr[mi_][1] = *(const short8*)&sm[(DOFF) + aBase + ((mh)*4 + mi_) * 1024 + sw1]; \
    }

#define RD_B(bx, DOFF, n0) \
    _Pragma("unroll") \
    for (int ni_ = 0; ni_ < 2; ++ni_) { \
        bx[ni_][0] = *(const short8*)&sm[(DOFF) + bBase + ((n0) + ni_) * 1024 + sw0]; \
        bx[ni_][1] = *(const short8*)&sm[(DOFF) + bBase + ((n0) + ni_) * 1024 + sw1]; \
    }

#define QUADX(af, bx, mh, nh) \
    __builtin_amdgcn_s_setprio(1); \
    _Pragma("unroll") \
    for (int s_ = 0; s_ < 2; ++s_) { \
      _Pragma("unroll") \
      for (int mi_ = 0; mi_ < 4; ++mi_) { \
        _Pragma("unroll") \
        for (int ni_ = 0; ni_ < 2; ++ni_) { \
          acc[(mh)*4+mi_][(nh)*2+ni_] = __builtin_amdgcn_mfma_f32_16x16x32_bf16( \
            __builtin_bit_cast(bf16x8, af[mi_][s_]), \
            __builtin_bit_cast(bf16x8, bx[ni_][s_]), \
            acc[(mh)*4+mi_][(nh)*2+ni_], 0, 0, 0); \
        } } }

__global__ __launch_bounds__(512, 2) void gemm256(const unsigned short* __restrict__ A,
                                                  const unsigned short* __restrict__ B,
                                                  const float* __restrict__ bias,
                                                  float* __restrict__ C) {
    __shared__ __align__(16) unsigned short sm[65536];   // 128 KiB

    const int tid = threadIdx.x;
    const int w64 = tid >> 6;
    const int lane = tid & 63;

    // T1: bijective XCD swizzle (gridDim.x % 8 == 0)
    const int nwg = gridDim.x;
    const int chunk = nwg >> 3;
    const int s_id = (blockIdx.x & 7) * chunk + (blockIdx.x >> 3);
    const int nm = nwg >> 4;              // M tiles (N tiles fixed at 16)
    const int bm = s_id % nm;
    const int bn = s_id / nm;
    const int row0 = bm * 256;
    const int col0 = bn * 256;

    const int wr = w64 >> 2;              // 0..1 (M half: 128 rows)
    const int wc = w64 & 3;               // 0..3 (N quarter: 64 cols)

    // ---- stage addressing (proven): row srow(+64,+128h), swizzled k
    const int srow = tid >> 3;                                  // 0..63
    const int swzk = 8 * ((tid & 7) ^ ((tid >> 3) & 7));        // pre-swizzled src elem
    const unsigned short* srcA = A + (size_t)(row0 + srow) * KDIM + swzk;
    const unsigned short* srcB = B + (size_t)(col0 + srow) * KDIM + swzk;

    // ---- frag addressing (proven, 0 conflicts)
    const int lr = lane & 15;
    const int lk4 = lane >> 4;
    const int l7 = lane & 7;
    const int sw0 = 8 * (((0 << 2) + lk4) ^ l7);
    const int sw1 = 8 * (((1 << 2) + lk4) ^ l7);
    const int aBase = (wr * 128 + lr) * 64;
    const int bBase = 16384 + (wc * 64 + lr) * 64;

    f32x4 acc[8][4] = {};
    short8 aF[4][2], aG[4][2], bQ0[2][2], bQ1[2][2];

    auto stageA = [&](int hh, int tile, int db) {
        const unsigned short* g = srcA + (size_t)hh * 128 * KDIM + (size_t)tile * 64;
        unsigned short* l = &sm[db * 32768 + hh * 8192 + w64 * 512];
        gload_lds16(g, l);
        gload_lds16(g + (size_t)64 * KDIM, l + 4096);
    };
    auto stageB = [&](int hh, int tile, int db) {
        const unsigned short* g = srcB + (size_t)hh * 128 * KDIM + (size_t)tile * 64;
        unsigned short* l = &sm[db * 32768 + 16384 + hh * 8192 + w64 * 512];
        gload_lds16(g, l);
        gload_lds16(g + (size_t)64 * KDIM, l + 4096);
    };

    const int NT = KDIM / 64;   // 64 K-tiles (even)

    // ---- prologue: tile0 -> buf0 (8 loads), tile1.B -> buf1 (4 loads)
    stageB(0, 0, 0); stageB(1, 0, 0); stageA(0, 0, 0); stageA(1, 0, 0);
    stageB(0, 1, 1); stageB(1, 1, 1);
    VMCNT(4)                    // buf0 fully resident; B(1)4 in flight = invariant
    __builtin_amdgcn_s_barrier();
    RD_A(aF, 0, 0)              // reads for iter0 P1 (buf0 resident)
    RD_B(bQ0, 0, 0)

    for (int i = 0; i < NT / 2; ++i) {
        const int e = 2 * i;
        const int o = e + 1;
        const int e2 = (e + 2 < NT) ? e + 2 : e;   // clamp: byte-idempotent restage
        const int o2 = (o + 2 < NT) ? o + 2 : o;

        // ===== P1: stage A0(o),A1(o)->buf1; MFMA Q00(e); read-behind bQ1(e) =====
        stageA(0, o, 1);
        stageA(1, o, 1);
        PH_BAR
        QUADX(aF, bQ0, 0, 0)
        RD_B(bQ1, 0, 2)
        PH_END
        // ===== P2: MFMA Q01(e); read-behind aG(e) =====
        PH_BAR
        QUADX(aF, bQ1, 0, 1)
        RD_A(aG, 0, 1)
        PH_END
        // ===== P3: stage B0(e+2)->buf0; MFMA Q10(e) =====
        stageB(0, e2, 0);
        PH_BAR
        QUADX(aG, bQ0, 1, 0)
        PH_END
        // ===== P4: stage B1(e+2),A0(e+2)->buf0; vmcnt(6) => tile o resident;
        //          MFMA Q11(e); read-behind aF(o), bQ0(o) =====
        stageB(1, e2, 0);
        stageA(0, e2, 0);
        VMCNT(6)
        PH_BAR
        QUADX(aG, bQ1, 1, 1)
        RD_A(aF, 32768, 0)
        RD_B(bQ0, 32768, 0)
        PH_END

        // ===== P5: stage A1(e+2)->buf0; MFMA Q00(o); read-behind bQ1(o) =====
        stageA(1, e2, 0);
        PH_BAR
        QUADX(aF, bQ0, 0, 0)
        RD_B(bQ1, 32768, 2)
        PH_END
        // ===== P6: MFMA Q01(o); read-behind aG(o) =====
        PH_BAR
        QUADX(aF, bQ1, 0, 1)
        RD_A(aG, 32768, 1)
        PH_END
        // ===== P7: stage B0(o+2)->buf1; MFMA Q10(o) =====
        stageB(0, o2, 1);
        PH_BAR
        QUADX(aG, bQ0, 1, 0)
        PH_END
        // ===== P8: stage B1(o+2)->buf1; vmcnt(4) => buf0(e+2) resident;
        //          MFMA Q11(o); read-behind aF(e2), bQ0(e2) =====
        stageB(1, o2, 1);
        VMCNT(4)
        PH_BAR
        QUADX(aG, bQ1, 1, 1)
        RD_A(aF, 0, 0)
        RD_B(bQ0, 0, 0)
        PH_END
    }

    // no LDS-DMA / dangling reads may outlive the loop
    __builtin_amdgcn_sched_barrier(0);
    asm volatile("s_waitcnt vmcnt(0) lgkmcnt(0)" ::: "memory");
    __builtin_amdgcn_sched_barrier(0);

    // ---- epilogue: C/D layout col=lane&15, row=(lane>>4)*4+r
#pragma unroll
    for (int m = 0; m < 8; ++m) {
#pragma unroll
        for (int n = 0; n < 4; ++n) {
            int col = col0 + wc * 64 + n * 16 + lr;
            float bz = bias[col];
#pragma unroll
            for (int r = 0; r < 4; ++r) {
                int row = row0 + wr * 128 + m * 16 + lk4 * 4 + r;
                C[(size_t)row * NDIM + col] = acc[m][n][r] + bz;
            }
        }
    }
}

// ---------------- emergency fallback (ws too small / odd shape): exact fp32 ----------------
__global__ void fallback_kernel(const float* __restrict__ x, const int* __restrict__ wp,
                                const float* __restrict__ scales, const float* __restrict__ zeros,
                                const float* __restrict__ bias, float* __restrict__ out) {
    int o = blockIdx.x * 256 + threadIdx.x;
    int m = blockIdx.y;
    __shared__ float xs[KDIM];
    for (int i = threadIdx.x; i < KDIM; i += 256) xs[i] = x[(size_t)m * KDIM + i];
    __syncthreads();
    float acc = 0.f;
    for (int g = 0; g < 32; ++g) {
        float s = scales[o * 32 + g], z = zeros[o * 32 + g];
        float aq = 0.f, ax = 0.f;
        for (int j = 0; j < 32; ++j) {
            int p = wp[o * 1024 + g * 32 + j];
            int kb = g * 128 + j * 4;
#pragma unroll
            for (int q = 0; q < 4; ++q) {
                float xv = xs[kb + q];
                aq += xv * (float)((p >> (2 * q)) & 3);
                ax += xv;
            }
        }
        acc += s * aq + z * ax;
    }
    out[(size_t)m * NDIM + o] = acc + bias[o];
}

extern "C" void kernel_launch(void* const* d_in, const int* in_sizes, int n_in,
                              void* d_out, int out_size, void* d_ws, size_t ws_size,
                              hipStream_t stream) {
    const float* x      = (const float*)d_in[0];
    const int*   wp     = (const int*)d_in[1];
    const float* scales = (const float*)d_in[2];
    const float* zeros  = (const float*)d_in[3];
    const float* bias   = (const float*)d_in[4];
    float* out = (float*)d_out;

    const long M = (long)in_sizes[0] / KDIM;            // 8192
    const long PACKED = (long)in_sizes[1];              // 4194304
    const size_t need = (size_t)M * KDIM * 2 + (size_t)NDIM * KDIM * 2;  // 96 MB

    if (ws_size >= need && (M % 256) == 0) {
        unsigned short* xb = (unsigned short*)d_ws;
        unsigned short* wb = xb + (size_t)M * KDIM;
        cvt_x_kernel<<<(M * KDIM / 8) / 256, 256, 0, stream>>>(x, xb);
        dequant_w_kernel<<<(PACKED / 2) / 256, 256, 0, stream>>>(wp, scales, zeros, wb);
        int nwg = (int)(M / 256) * (NDIM / 256);        // 32*16 = 512, %8==0
        gemm256<<<nwg, 512, 0, stream>>>(xb, wb, bias, out);
    } else {
        dim3 grid(NDIM / 256, M);
        fallback_kernel<<<grid, 256, 0, stream>>>(x, wp, scales, zeros, bias, out);
    }
}

// Round 15
// 283.143 us; speedup vs baseline: 1.0088x; 1.0088x over previous
//
#include <hip/hip_runtime.h>
#include <hip/hip_bf16.h>
#include <cstdint>
#include <cstddef>

#define KDIM 4096   // IN_F
#define NDIM 4096   // OUT_F

typedef __attribute__((ext_vector_type(8))) short short8;
typedef __attribute__((ext_vector_type(8))) __bf16 bf16x8;
typedef __attribute__((ext_vector_type(4))) float f32x4;

// f32 -> bf16, round-to-nearest-even
__device__ __forceinline__ unsigned short bf16_rne(float f) {
    unsigned int u = __builtin_bit_cast(unsigned int, f);
    u += 0x7fffu + ((u >> 16) & 1u);
    return (unsigned short)(u >> 16);
}

__device__ __forceinline__ void gload_lds16(const unsigned short* g, unsigned short* l) {
    __builtin_amdgcn_global_load_lds(
        (const __attribute__((address_space(1))) unsigned int*)g,
        (__attribute__((address_space(3))) unsigned int*)l,
        16, 0, 0);
}

// ---------------- fused preprocess (R15): x f32->bf16 AND 2-bit W -> bf16 [N][K]
// Block-range split: blocks [0, nbx) convert x (8 f32/thread);
// blocks [nbx, nbx+nbw) dequant weights (2 packed ints = 8 weights/thread).
// One launch instead of two: saves a launch gap; streams overlap in the
// memory system. Per-thread logic identical to the R14 kernels (proven).
__global__ void prep_kernel(const float* __restrict__ x, unsigned short* __restrict__ xb,
                            const int* __restrict__ wp,
                            const float* __restrict__ scales,
                            const float* __restrict__ zeros,
                            unsigned short* __restrict__ wb,
                            int nbx) {
    if ((int)blockIdx.x < nbx) {
        long i = (long)blockIdx.x * blockDim.x + threadIdx.x;   // one thread = 8 elems
        float4 a = ((const float4*)x)[2 * i];
        float4 b = ((const float4*)x)[2 * i + 1];
        union { unsigned short u[8]; short8 v; } r;
        r.u[0] = bf16_rne(a.x); r.u[1] = bf16_rne(a.y);
        r.u[2] = bf16_rne(a.z); r.u[3] = bf16_rne(a.w);
        r.u[4] = bf16_rne(b.x); r.u[5] = bf16_rne(b.y);
        r.u[6] = bf16_rne(b.z); r.u[7] = bf16_rne(b.w);
        ((short8*)xb)[i] = r.v;
    } else {
        long i = (long)(blockIdx.x - nbx) * blockDim.x + threadIdx.x;  // 2 packed ints = 8 weights
        int2 p = ((const int2*)wp)[i];
        long base = i * 8;                    // flat weight index (o*4096 + k)
        int o = (int)(base >> 12);
        int g = (int)((base & 4095) >> 7);    // all 8 weights in same group (8 | 128)
        float s = scales[o * 32 + g];
        float z = zeros[o * 32 + g];
        union { unsigned short u[8]; short8 v; } r;
#pragma unroll
        for (int j = 0; j < 4; ++j) {
            r.u[j]     = bf16_rne((float)((p.x >> (2 * j)) & 3) * s + z);
            r.u[4 + j] = bf16_rne((float)((p.y >> (2 * j)) & 3) * s + z);
        }
        ((short8*)wb)[i] = r.v;
    }
}

// ---------------- 256x256 8-phase GEMM, READ-BEHIND (R14, unchanged) ----------------
// C[M][N] = A[M][K](bf16) * B[N][K](bf16)^T + bias.
// Best-of-session schedule (R14): stage ring + vmcnt constants of R11/R12;
// ds_reads placed AFTER each phase's MFMA cluster, feeding the NEXT phase's
// MFMAs — reads drain under the MFMA epoch + barrier wait.
//
// READ MAP (reads at phase END, consumed next phase):
//  prologue: aF(0), bQ0(0).
//  P1-end: bQ1(e)[4]   P2-end: aG(e)[8]    P3-end: --
//  P4-end (after vmcnt6+bar => buf1 resident): aF(o)[8], bQ0(o)[4]
//  P5-end: bQ1(o)[4]   P6-end: aG(o)[8]    P7-end: --
//  P8-end (after vmcnt4+bar => buf0(e+2) resident): aF(e2)[8], bQ0(e2)[4]
// REGISTER WAR (rewrite after last use): bQ1 P1w/P2u/P5w; aG P2w/P3,P4u/P6w;
//  aF P4w/P5,P6u/P8w; bQ0 P4w/P5,P7u/P8w. All per-wave program order. OK.
// LDS W-A-R: each read returns before its consumer MFMA (compiler lgkm gate)
//  < that phase's end barrier < the overwriting stage. Verified per region.
// STAGE RING + VMCNT: P1: A0(o),A1(o)->buf1 | P3: B0(e2) | P4: B1(e2),A0(e2),
//  VMCNT(6) => tile o resident | P5: A1(e2) | P7: B0(o2) | P8: B1(o2),
//  VMCNT(4) => buf0(e+2) resident. Prologue: tile0(8)->buf0, B(1)(4)->buf1,
//  vmcnt(4). Tail: clamp => byte-idempotent restage; post-loop vmcnt+lgkm(0).
// Swizzle (proven, 0 conflicts): LDS(r,8j)=G(r,8*(j^(r&7))); read elem
//  R*64 + 8*((4s+lk4)^(R&7)), R&7 == lane&7.

#define PH_BAR \
    __builtin_amdgcn_s_barrier();

#define PH_END \
    __builtin_amdgcn_s_setprio(0); \
    __builtin_amdgcn_sched_barrier(0); \
    __builtin_amdgcn_s_barrier();

#define VMCNT(N) \
    __builtin_amdgcn_sched_barrier(0); \
    asm volatile("s_waitcnt vmcnt(" #N ")" ::: "memory"); \
    __builtin_amdgcn_sched_barrier(0);

#define RD_A(arr, DOFF, mh) \
    _Pragma("unroll") \
    for (int mi_ = 0; mi_ < 4; ++mi_) { \
        arr[mi_][0] = *(const short8*)&sm[(DOFF) + aBase + ((mh)*4 + mi_) * 1024 + sw0]; \
        arr[mi_][1] = *(const short8*)&sm[(DOFF) + aBase + ((mh)*4 + mi_) * 1024 + sw1]; \
    }

#define RD_B(bx, DOFF, n0) \
    _Pragma("unroll") \
    for (int ni_ = 0; ni_ < 2; ++ni_) { \
        bx[ni_][0] = *(const short8*)&sm[(DOFF) + bBase + ((n0) + ni_) * 1024 + sw0]; \
        bx[ni_][1] = *(const short8*)&sm[(DOFF) + bBase + ((n0) + ni_) * 1024 + sw1]; \
    }

#define QUADX(af, bx, mh, nh) \
    __builtin_amdgcn_s_setprio(1); \
    _Pragma("unroll") \
    for (int s_ = 0; s_ < 2; ++s_) { \
      _Pragma("unroll") \
      for (int mi_ = 0; mi_ < 4; ++mi_) { \
        _Pragma("unroll") \
        for (int ni_ = 0; ni_ < 2; ++ni_) { \
          acc[(mh)*4+mi_][(nh)*2+ni_] = __builtin_amdgcn_mfma_f32_16x16x32_bf16( \
            __builtin_bit_cast(bf16x8, af[mi_][s_]), \
            __builtin_bit_cast(bf16x8, bx[ni_][s_]), \
            acc[(mh)*4+mi_][(nh)*2+ni_], 0, 0, 0); \
        } } }

__global__ __launch_bounds__(512, 2) void gemm256(const unsigned short* __restrict__ A,
                                                  const unsigned short* __restrict__ B,
                                                  const float* __restrict__ bias,
                                                  float* __restrict__ C) {
    __shared__ __align__(16) unsigned short sm[65536];   // 128 KiB

    const int tid = threadIdx.x;
    const int w64 = tid >> 6;
    const int lane = tid & 63;

    // T1: bijective XCD swizzle (gridDim.x % 8 == 0)
    const int nwg = gridDim.x;
    const int chunk = nwg >> 3;
    const int s_id = (blockIdx.x & 7) * chunk + (blockIdx.x >> 3);
    const int nm = nwg >> 4;              // M tiles (N tiles fixed at 16)
    const int bm = s_id % nm;
    const int bn = s_id / nm;
    const int row0 = bm * 256;
    const int col0 = bn * 256;

    const int wr = w64 >> 2;              // 0..1 (M half: 128 rows)
    const int wc = w64 & 3;               // 0..3 (N quarter: 64 cols)

    // ---- stage addressing (proven): row srow(+64,+128h), swizzled k
    const int srow = tid >> 3;                                  // 0..63
    const int swzk = 8 * ((tid & 7) ^ ((tid >> 3) & 7));        // pre-swizzled src elem
    const unsigned short* srcA = A + (size_t)(row0 + srow) * KDIM + swzk;
    const unsigned short* srcB = B + (size_t)(col0 + srow) * KDIM + swzk;

    // ---- frag addressing (proven, 0 conflicts)
    const int lr = lane & 15;
    const int lk4 = lane >> 4;
    const int l7 = lane & 7;
    const int sw0 = 8 * (((0 << 2) + lk4) ^ l7);
    const int sw1 = 8 * (((1 << 2) + lk4) ^ l7);
    const int aBase = (wr * 128 + lr) * 64;
    const int bBase = 16384 + (wc * 64 + lr) * 64;

    f32x4 acc[8][4] = {};
    short8 aF[4][2], aG[4][2], bQ0[2][2], bQ1[2][2];

    auto stageA = [&](int hh, int tile, int db) {
        const unsigned short* g = srcA + (size_t)hh * 128 * KDIM + (size_t)tile * 64;
        unsigned short* l = &sm[db * 32768 + hh * 8192 + w64 * 512];
        gload_lds16(g, l);
        gload_lds16(g + (size_t)64 * KDIM, l + 4096);
    };
    auto stageB = [&](int hh, int tile, int db) {
        const unsigned short* g = srcB + (size_t)hh * 128 * KDIM + (size_t)tile * 64;
        unsigned short* l = &sm[db * 32768 + 16384 + hh * 8192 + w64 * 512];
        gload_lds16(g, l);
        gload_lds16(g + (size_t)64 * KDIM, l + 4096);
    };

    const int NT = KDIM / 64;   // 64 K-tiles (even)

    // ---- prologue: tile0 -> buf0 (8 loads), tile1.B -> buf1 (4 loads)
    stageB(0, 0, 0); stageB(1, 0, 0); stageA(0, 0, 0); stageA(1, 0, 0);
    stageB(0, 1, 1); stageB(1, 1, 1);
    VMCNT(4)                    // buf0 fully resident; B(1)4 in flight = invariant
    __builtin_amdgcn_s_barrier();
    RD_A(aF, 0, 0)              // reads for iter0 P1 (buf0 resident)
    RD_B(bQ0, 0, 0)

    for (int i = 0; i < NT / 2; ++i) {
        const int e = 2 * i;
        const int o = e + 1;
        const int e2 = (e + 2 < NT) ? e + 2 : e;   // clamp: byte-idempotent restage
        const int o2 = (o + 2 < NT) ? o + 2 : o;

        // ===== P1: stage A0(o),A1(o)->buf1; MFMA Q00(e); read-behind bQ1(e) =====
        stageA(0, o, 1);
        stageA(1, o, 1);
        PH_BAR
        QUADX(aF, bQ0, 0, 0)
        RD_B(bQ1, 0, 2)
        PH_END
        // ===== P2: MFMA Q01(e); read-behind aG(e) =====
        PH_BAR
        QUADX(aF, bQ1, 0, 1)
        RD_A(aG, 0, 1)
        PH_END
        // ===== P3: stage B0(e+2)->buf0; MFMA Q10(e) =====
        stageB(0, e2, 0);
        PH_BAR
        QUADX(aG, bQ0, 1, 0)
        PH_END
        // ===== P4: stage B1(e+2),A0(e+2)->buf0; vmcnt(6) => tile o resident;
        //          MFMA Q11(e); read-behind aF(o), bQ0(o) =====
        stageB(1, e2, 0);
        stageA(0, e2, 0);
        VMCNT(6)
        PH_BAR
        QUADX(aG, bQ1, 1, 1)
        RD_A(aF, 32768, 0)
        RD_B(bQ0, 32768, 0)
        PH_END

        // ===== P5: stage A1(e+2)->buf0; MFMA Q00(o); read-behind bQ1(o) =====
        stageA(1, e2, 0);
        PH_BAR
        QUADX(aF, bQ0, 0, 0)
        RD_B(bQ1, 32768, 2)
        PH_END
        // ===== P6: MFMA Q01(o); read-behind aG(o) =====
        PH_BAR
        QUADX(aF, bQ1, 0, 1)
        RD_A(aG, 32768, 1)
        PH_END
        // ===== P7: stage B0(o+2)->buf1; MFMA Q10(o) =====
        stageB(0, o2, 1);
        PH_BAR
        QUADX(aG, bQ0, 1, 0)
        PH_END
        // ===== P8: stage B1(o+2)->buf1; vmcnt(4) => buf0(e+2) resident;
        //          MFMA Q11(o); read-behind aF(e2), bQ0(e2) =====
        stageB(1, o2, 1);
        VMCNT(4)
        PH_BAR
        QUADX(aG, bQ1, 1, 1)
        RD_A(aF, 0, 0)
        RD_B(bQ0, 0, 0)
        PH_END
    }

    // no LDS-DMA / dangling reads may outlive the loop
    __builtin_amdgcn_sched_barrier(0);
    asm volatile("s_waitcnt vmcnt(0) lgkmcnt(0)" ::: "memory");
    __builtin_amdgcn_sched_barrier(0);

    // ---- epilogue: C/D layout col=lane&15, row=(lane>>4)*4+r
#pragma unroll
    for (int m = 0; m < 8; ++m) {
#pragma unroll
        for (int n = 0; n < 4; ++n) {
            int col = col0 + wc * 64 + n * 16 + lr;
            float bz = bias[col];
#pragma unroll
            for (int r = 0; r < 4; ++r) {
                int row = row0 + wr * 128 + m * 16 + lk4 * 4 + r;
                C[(size_t)row * NDIM + col] = acc[m][n][r] + bz;
            }
        }
    }
}

// ---------------- emergency fallback (ws too small / odd shape): exact fp32 ----------------
__global__ void fallback_kernel(const float* __restrict__ x, const int* __restrict__ wp,
                                const float* __restrict__ scales, const float* __restrict__ zeros,
                                const float* __restrict__ bias, float* __restrict__ out) {
    int o = blockIdx.x * 256 + threadIdx.x;
    int m = blockIdx.y;
    __shared__ float xs[KDIM];
    for (int i = threadIdx.x; i < KDIM; i += 256) xs[i] = x[(size_t)m * KDIM + i];
    __syncthreads();
    float acc = 0.f;
    for (int g = 0; g < 32; ++g) {
        float s = scales[o * 32 + g], z = zeros[o * 32 + g];
        float aq = 0.f, ax = 0.f;
        for (int j = 0; j < 32; ++j) {
            int p = wp[o * 1024 + g * 32 + j];
            int kb = g * 128 + j * 4;
#pragma unroll
            for (int q = 0; q < 4; ++q) {
                float xv = xs[kb + q];
                aq += xv * (float)((p >> (2 * q)) & 3);
                ax += xv;
            }
        }
        acc += s * aq + z * ax;
    }
    out[(size_t)m * NDIM + o] = acc + bias[o];
}

extern "C" void kernel_launch(void* const* d_in, const int* in_sizes, int n_in,
                              void* d_out, int out_size, void* d_ws, size_t ws_size,
                              hipStream_t stream) {
    const float* x      = (const float*)d_in[0];
    const int*   wp     = (const int*)d_in[1];
    const float* scales = (const float*)d_in[2];
    const float* zeros  = (const float*)d_in[3];
    const float* bias   = (const float*)d_in[4];
    float* out = (float*)d_out;

    const long M = (long)in_sizes[0] / KDIM;            // 8192
    const long PACKED = (long)in_sizes[1];              // 4194304
    const size_t need = (size_t)M * KDIM * 2 + (size_t)NDIM * KDIM * 2;  // 96 MB

    if (ws_size >= need && (M % 256) == 0) {
        unsigned short* xb = (unsigned short*)d_ws;
        unsigned short* wb = xb + (size_t)M * KDIM;
        int nbx = (int)((M * KDIM / 8) / 256);          // 16384 x-blocks
        int nbw = (int)((PACKED / 2) / 256);            // 8192 w-blocks
        prep_kernel<<<nbx + nbw, 256, 0, stream>>>(x, xb, wp, scales, zeros, wb, nbx);
        int nwg = (int)(M / 256) * (NDIM / 256);        // 32*16 = 512, %8==0
        gemm256<<<nwg, 512, 0, stream>>>(xb, wb, bias, out);
    } else {
        dim3 grid(NDIM / 256, M);
        fallback_kernel<<<grid, 256, 0, stream>>>(x, wp, scales, zeros, bias, out);
    }
}

// Round 16
// 236.751 us; speedup vs baseline: 1.2064x; 1.1960x over previous
//
#include <hip/hip_runtime.h>
#include <hip/hip_bf16.h>
#include <cstdint>
#include <cstddef>

#define KDIM 4096   // IN_F
#define NDIM 4096   // OUT_F
#define NG 32       // groups per row
#define GRP 128     // group size == BK

typedef __attribute__((ext_vector_type(8))) short short8;
typedef __attribute__((ext_vector_type(8))) __bf16 bf16x8;
typedef __attribute__((ext_vector_type(4))) float f32x4;
typedef __attribute__((ext_vector_type(4))) int i32x4;

__device__ __forceinline__ unsigned short bf16_rne(float f) {
    unsigned int u = __builtin_bit_cast(unsigned int, f);
    u += 0x7fffu + ((u >> 16) & 1u);
    return (unsigned short)(u >> 16);
}

__device__ __forceinline__ void gload16(const void* g, void* l) {
    __builtin_amdgcn_global_load_lds(
        (const __attribute__((address_space(1))) unsigned int*)g,
        (__attribute__((address_space(3))) unsigned int*)l,
        16, 0, 0);
}

// ============ prep (R16): x->i8 per-row + group sums; W 2-bit->i8; z->bf16; scales->transposed f32
// range1 [0,nbx): one block per x row: absmax -> a_m, quantize 16 elems/thread,
//   exact f32 group sums -> S bf16.  range2: unpack 16 weights/thread (no dequant!).
//   range3: zb bf16 + st[g][N] transpose.
__global__ void prep_kernel(const float* __restrict__ x, const int* __restrict__ wp,
                            const float* __restrict__ scales, const float* __restrict__ zeros,
                            signed char* __restrict__ xq, signed char* __restrict__ wq,
                            unsigned short* __restrict__ Sb, float* __restrict__ arow,
                            unsigned short* __restrict__ zb, float* __restrict__ st,
                            int nbx, int nbw) {
    const int b = blockIdx.x;
    const int t = threadIdx.x;
    if (b < nbx) {
        __shared__ float red[256];
        __shared__ float gs[256];
        const float4* xr = (const float4*)(x + (size_t)b * KDIM);
        float4 v[4];
        float mx = 0.f, sum = 0.f;
#pragma unroll
        for (int j = 0; j < 4; ++j) {
            v[j] = xr[t * 4 + j];
            mx = fmaxf(mx, fmaxf(fmaxf(fabsf(v[j].x), fabsf(v[j].y)),
                                 fmaxf(fabsf(v[j].z), fabsf(v[j].w))));
            sum += v[j].x + v[j].y + v[j].z + v[j].w;
        }
        red[t] = mx; gs[t] = sum;
        __syncthreads();
        for (int s = 128; s > 0; s >>= 1) {
            if (t < s) red[t] = fmaxf(red[t], red[t + s]);
            __syncthreads();
        }
        const float amax = red[0];
        const float inv = (amax > 0.f) ? 127.f / amax : 0.f;
        union { signed char c[16]; i32x4 q; } o;
#pragma unroll
        for (int j = 0; j < 4; ++j) {
            o.c[4 * j + 0] = (signed char)(int)rintf(v[j].x * inv);
            o.c[4 * j + 1] = (signed char)(int)rintf(v[j].y * inv);
            o.c[4 * j + 2] = (signed char)(int)rintf(v[j].z * inv);
            o.c[4 * j + 3] = (signed char)(int)rintf(v[j].w * inv);
        }
        ((i32x4*)(xq + (size_t)b * KDIM))[t] = o.q;
        if (t < NG) {   // thread t sums group t (8 sub-sums of 16)
            float s8 = 0.f;
#pragma unroll
            for (int j = 0; j < 8; ++j) s8 += gs[t * 8 + j];
            Sb[(size_t)b * NG + t] = bf16_rne(s8);
        }
        if (t == 0) arow[b] = amax * (1.f / 127.f);
    } else if (b < nbx + nbw) {
        long i = (long)(b - nbx) * 256 + t;   // 4 packed ints = 16 weights
        int4 p = ((const int4*)wp)[i];
        union { signed char c[16]; i32x4 q; } o;
#pragma unroll
        for (int j = 0; j < 4; ++j) {
            o.c[j]      = (signed char)((p.x >> (2 * j)) & 3);
            o.c[4 + j]  = (signed char)((p.y >> (2 * j)) & 3);
            o.c[8 + j]  = (signed char)((p.z >> (2 * j)) & 3);
            o.c[12 + j] = (signed char)((p.w >> (2 * j)) & 3);
        }
        ((i32x4*)wq)[i] = o.q;
    } else {
        long i = (long)(b - nbx - nbw) * 256 + t;   // one (o,g)
        int oo = (int)(i >> 5), g = (int)(i & 31);
        zb[i] = bf16_rne(zeros[i]);
        st[(size_t)g * NDIM + oo] = scales[i];
    }
}

// ============ i8 GEMM (R16): 256x256 tile, BK=128=GROUP, free-run ring (R6-proven shape)
// acc_f32[m][n] += s[o,g] * i32mfma(qx, qw over group g); epilogue: *= a_row,
// += z-term via ONE bf16 16x16x32 MFMA tile (C-in = scaled acc), += bias.
// SYNC LEDGER (free-run, proven R6): per tile: {24 b128 + 4 s-ds_read ->
//  64 i8-MFMA + rescale (data-dep: all LDS reads consumed before B1)};
//  B1; stage tile t+2 (9 gloads: A4,B4,S1; S idempotent across 8 waves);
//  vmcnt(9) drains tile t+1's 9; B2 => t+1 resident cross-wave.
//  Tail: t2 clamped to t => byte-idempotent restage. Post-loop vmcnt(0).
// Swizzle (byte-identical to proven R4/R14 pattern, rows 128B):
//  LDS(r, 16B-seg p) = G(r, seg p^(r&7)) via pre-swizzled source; read segs
//  lk4 (k 0..63) and 4+lk4 (k 64..127), XOR lane&7 == r&7. 0 conflicts.
// i8 frag assumption (by analogy with verified bf16 16x16x32): A row=lane&15,
//  k = (lane>>4)*16 + 0..15 contiguous bytes; B col=lane&15 same k.
//  C/D layout shape-determined (verified dtype-independent, m121-128).

#define WGBAR \
    __builtin_amdgcn_sched_barrier(0); \
    __builtin_amdgcn_s_barrier(); \
    __builtin_amdgcn_sched_barrier(0);

#define VMCNT(N) \
    __builtin_amdgcn_sched_barrier(0); \
    asm volatile("s_waitcnt vmcnt(" #N ")" ::: "memory"); \
    __builtin_amdgcn_sched_barrier(0);

__global__ __launch_bounds__(512, 2) void gemm_i8(const signed char* __restrict__ A,
                                                  const signed char* __restrict__ B,
                                                  const unsigned short* __restrict__ Sb,
                                                  const float* __restrict__ arow,
                                                  const unsigned short* __restrict__ zb,
                                                  const float* __restrict__ st,
                                                  const float* __restrict__ bias,
                                                  float* __restrict__ C) {
    __shared__ __align__(16) signed char sm[133120];  // 2 bufs x 66560: A 32K | B 32K | S 1K

    const int tid = threadIdx.x;
    const int w64 = tid >> 6;
    const int lane = tid & 63;

    // T1: bijective XCD swizzle (gridDim.x % 8 == 0)
    const int nwg = gridDim.x;
    const int chunk = nwg >> 3;
    const int s_id = (blockIdx.x & 7) * chunk + (blockIdx.x >> 3);
    const int nm = nwg >> 4;              // M tiles (N tiles = 16)
    const int bm = s_id % nm;
    const int bn = s_id / nm;
    const int row0 = bm * 256;
    const int col0 = bn * 256;

    const int wr = w64 >> 2;              // 0..1 (M half: 128 rows)
    const int wc = w64 & 3;               // 0..3 (N quarter: 64 cols)

    // ---- stage addressing: thread covers row tid>>3 (+64,+128h), 16B seg pre-swizzled
    const int srow = tid >> 3;
    const int sswz = 16 * ((tid & 7) ^ (srow & 7));
    const signed char* srcA = A + (size_t)(row0 + srow) * KDIM + sswz;
    const signed char* srcB = B + (size_t)(col0 + srow) * KDIM + sswz;
    const float* srcS = st + col0 + (lane << 2);       // + tile*NDIM; 16B/lane

    // ---- frag addressing (0 conflicts, same byte math as proven bf16 pattern)
    const int lr = lane & 15;
    const int lk4 = lane >> 4;
    const int l7 = lane & 7;
    const int sw0 = 16 * (lk4 ^ l7);          // k 0..63 chunk
    const int sw1 = 16 * ((4 + lk4) ^ l7);    // k 64..127 chunk
    const int aBase = (wr * 128 + lr) * 128;
    const int bBase = 32768 + (wc * 64 + lr) * 128;

    f32x4 acc[8][4] = {};

    auto stageA = [&](int hh, int tile, int db) {
        const signed char* g = srcA + (size_t)hh * 128 * KDIM + (size_t)tile * 128;
        signed char* l = &sm[db * 66560 + hh * 16384 + w64 * 1024];
        gload16(g, l);
        gload16(g + (size_t)64 * KDIM, l + 8192);
    };
    auto stageB = [&](int hh, int tile, int db) {
        const signed char* g = srcB + (size_t)hh * 128 * KDIM + (size_t)tile * 128;
        signed char* l = &sm[db * 66560 + 32768 + hh * 16384 + w64 * 1024];
        gload16(g, l);
        gload16(g + (size_t)64 * KDIM, l + 8192);
    };
    auto stageS = [&](int tile, int db) {   // 1KB scale slice; all 8 waves duplicate (idempotent)
        gload16(srcS + (size_t)tile * NDIM, &sm[db * 66560 + 65536]);
    };

    const int NT = KDIM / GRP;   // 32 K-tiles; tile index == group index

    // ---- prologue: tile0 -> buf0, tile1 -> buf1 (9 gloads each)
    stageA(0, 0, 0); stageA(1, 0, 0); stageB(0, 0, 0); stageB(1, 0, 0); stageS(0, 0);
    stageA(0, 1, 1); stageA(1, 1, 1); stageB(0, 1, 1); stageB(1, 1, 1); stageS(1, 1);
    VMCNT(9)                     // tile0's 9 landed (tile1 in flight)
    WGBAR

    for (int t = 0; t < NT; ++t) {
        const int d = t & 1;
        const int dOff = d * 66560;
        const int t2 = (t + 2 < NT) ? t + 2 : t;   // clamped tail: byte-idempotent restage

        i32x4 bQ[4][2];
        float s4[4];
#pragma unroll
        for (int ni = 0; ni < 4; ++ni) {
            bQ[ni][0] = *(const i32x4*)&sm[dOff + bBase + ni * 2048 + sw0];
            bQ[ni][1] = *(const i32x4*)&sm[dOff + bBase + ni * 2048 + sw1];
        }
#pragma unroll
        for (int ni = 0; ni < 4; ++ni)
            s4[ni] = *(const float*)&sm[dOff + 65536 + (wc * 64 + ni * 16 + lr) * 4];

        __builtin_amdgcn_s_setprio(1);
#pragma unroll
        for (int mh = 0; mh < 2; ++mh) {
            i32x4 aF[4][2];
#pragma unroll
            for (int mi = 0; mi < 4; ++mi) {
                aF[mi][0] = *(const i32x4*)&sm[dOff + aBase + (mh * 4 + mi) * 2048 + sw0];
                aF[mi][1] = *(const i32x4*)&sm[dOff + aBase + (mh * 4 + mi) * 2048 + sw1];
            }
#pragma unroll
            for (int mi = 0; mi < 4; ++mi)
#pragma unroll
                for (int ni = 0; ni < 4; ++ni) {
                    i32x4 ai = __builtin_amdgcn_mfma_i32_16x16x64_i8(
                        aF[mi][0], bQ[ni][0], (i32x4){0, 0, 0, 0}, 0, 0, 0);
                    ai = __builtin_amdgcn_mfma_i32_16x16x64_i8(
                        aF[mi][1], bQ[ni][1], ai, 0, 0, 0);
#pragma unroll
                    for (int r = 0; r < 4; ++r)
                        acc[mh * 4 + mi][ni][r] += s4[ni] * (float)ai[r];
                }
        }
        __builtin_amdgcn_s_setprio(0);

        // ---- B1: all LDS reads of tile t consumed (data-dep) -> buf d free ----
        WGBAR
        stageA(0, t2, d); stageA(1, t2, d); stageB(0, t2, d); stageB(1, t2, d); stageS(t2, d);
        VMCNT(9)                 // drains tile t+1's 9 loads
        WGBAR                    // B2: tile t+1 resident cross-wave
    }

    // no LDS-DMA / dangling reads may outlive the loop
    __builtin_amdgcn_sched_barrier(0);
    asm volatile("s_waitcnt vmcnt(0) lgkmcnt(0)" ::: "memory");
    __builtin_amdgcn_sched_barrier(0);

    // ---- epilogue: acc = a_row*acc (i8 part), then z-term via bf16 MFMA (C-in), +bias
    float am[8][4];
#pragma unroll
    for (int m = 0; m < 8; ++m)
#pragma unroll
        for (int r = 0; r < 4; ++r)
            am[m][r] = arow[row0 + wr * 128 + m * 16 + lk4 * 4 + r];
#pragma unroll
    for (int m = 0; m < 8; ++m)
#pragma unroll
        for (int n = 0; n < 4; ++n)
#pragma unroll
            for (int r = 0; r < 4; ++r)
                acc[m][n][r] *= am[m][r];

    short8 aS[8], bZ[4];
#pragma unroll
    for (int m = 0; m < 8; ++m)
        aS[m] = *(const short8*)&Sb[(size_t)(row0 + wr * 128 + m * 16 + lr) * NG + lk4 * 8];
#pragma unroll
    for (int n = 0; n < 4; ++n)
        bZ[n] = *(const short8*)&zb[(size_t)(col0 + wc * 64 + n * 16 + lr) * NG + lk4 * 8];
#pragma unroll
    for (int m = 0; m < 8; ++m)
#pragma unroll
        for (int n = 0; n < 4; ++n)
            acc[m][n] = __builtin_amdgcn_mfma_f32_16x16x32_bf16(
                __builtin_bit_cast(bf16x8, aS[m]), __builtin_bit_cast(bf16x8, bZ[n]),
                acc[m][n], 0, 0, 0);

    // C/D layout col=lane&15, row=(lane>>4)*4+r (verified)
#pragma unroll
    for (int m = 0; m < 8; ++m) {
#pragma unroll
        for (int n = 0; n < 4; ++n) {
            int col = col0 + wc * 64 + n * 16 + lr;
            float bz = bias[col];
#pragma unroll
            for (int r = 0; r < 4; ++r) {
                int row = row0 + wr * 128 + m * 16 + lk4 * 4 + r;
                C[(size_t)row * NDIM + col] = acc[m][n][r] + bz;
            }
        }
    }
}

// ---------------- emergency fallback (ws too small / odd shape): exact fp32 ----------------
__global__ void fallback_kernel(const float* __restrict__ x, const int* __restrict__ wp,
                                const float* __restrict__ scales, const float* __restrict__ zeros,
                                const float* __restrict__ bias, float* __restrict__ out) {
    int o = blockIdx.x * 256 + threadIdx.x;
    int m = blockIdx.y;
    __shared__ float xs[KDIM];
    for (int i = threadIdx.x; i < KDIM; i += 256) xs[i] = x[(size_t)m * KDIM + i];
    __syncthreads();
    float acc = 0.f;
    for (int g = 0; g < 32; ++g) {
        float s = scales[o * 32 + g], z = zeros[o * 32 + g];
        float aq = 0.f, ax = 0.f;
        for (int j = 0; j < 32; ++j) {
            int p = wp[o * 1024 + g * 32 + j];
            int kb = g * 128 + j * 4;
#pragma unroll
            for (int q = 0; q < 4; ++q) {
                float xv = xs[kb + q];
                aq += xv * (float)((p >> (2 * q)) & 3);
                ax += xv;
            }
        }
        acc += s * aq + z * ax;
    }
    out[(size_t)m * NDIM + o] = acc + bias[o];
}

extern "C" void kernel_launch(void* const* d_in, const int* in_sizes, int n_in,
                              void* d_out, int out_size, void* d_ws, size_t ws_size,
                              hipStream_t stream) {
    const float* x      = (const float*)d_in[0];
    const int*   wp     = (const int*)d_in[1];
    const float* scales = (const float*)d_in[2];
    const float* zeros  = (const float*)d_in[3];
    const float* bias   = (const float*)d_in[4];
    float* out = (float*)d_out;

    const long M = (long)in_sizes[0] / KDIM;            // 8192
    const long PACKED = (long)in_sizes[1];              // 4194304

    // ws layout (bytes)
    const size_t xq_off = 0;
    const size_t wq_off = (size_t)M * KDIM;
    const size_t Sb_off = wq_off + (size_t)NDIM * KDIM;
    const size_t ar_off = Sb_off + (size_t)M * NG * 2;
    const size_t zb_off = ar_off + (size_t)M * 4;
    const size_t st_off = zb_off + (size_t)NDIM * NG * 2;
    const size_t need   = st_off + (size_t)NG * NDIM * 4;

    if (ws_size >= need && (M % 256) == 0) {
        signed char* xq = (signed char*)d_ws + xq_off;
        signed char* wq = (signed char*)d_ws + wq_off;
        unsigned short* Sb = (unsigned short*)((char*)d_ws + Sb_off);
        float* ar = (float*)((char*)d_ws + ar_off);
        unsigned short* zb = (unsigned short*)((char*)d_ws + zb_off);
        float* st = (float*)((char*)d_ws + st_off);

        int nbx = (int)M;                               // 8192 row blocks
        int nbw = (int)((NDIM * (long)KDIM / 16) / 256);// 4096 unpack blocks
        int nbz = (int)((NDIM * (long)NG) / 256);       // 512 z/st blocks
        prep_kernel<<<nbx + nbw + nbz, 256, 0, stream>>>(x, wp, scales, zeros,
                                                         xq, wq, Sb, ar, zb, st, nbx, nbw);
        int nwg = (int)(M / 256) * (NDIM / 256);        // 512, %8==0
        gemm_i8<<<nwg, 512, 0, stream>>>(xq, wq, Sb, ar, zb, st, bias, out);
    } else {
        dim3 grid(NDIM / 256, M);
        fallback_kernel<<<grid, 256, 0, stream>>>(x, wp, scales, zeros, bias, out);
    }
}